// Round 1
// baseline (786.707 us; speedup 1.0000x reference)
//
#include <hip/hip_runtime.h>
#include <hip/hip_bf16.h>
#include <stdint.h>

#define BATCH  64
#define NFRAME 32
#define NBOX   36
#define REGION 1024
#define HIDDEN 1024
#define ATTSZ  1024
#define FEAT2  3072
#define M_S (BATCH * NFRAME * NBOX)   // 73728
#define M_T (BATCH * NFRAME)          // 2048

typedef __attribute__((ext_vector_type(8))) short bf16x8;
typedef __attribute__((ext_vector_type(4))) float f32x4;

__device__ __forceinline__ unsigned short f2bf(float f) {
  union { float f; uint32_t u; } v; v.f = f;
  return (unsigned short)((v.u + 0x7FFFu + ((v.u >> 16) & 1u)) >> 16);  // RNE
}
__device__ __forceinline__ float bf2f(unsigned short u) {
  union { uint32_t u; float f; } v; v.u = (uint32_t)u << 16; return v.f;
}
__device__ __forceinline__ float fast_tanh(float x) {
  float e = __expf(2.f * x);
  return 1.f - 2.f / (e + 1.f);
}
__device__ __forceinline__ void gload_lds16(const unsigned short* g, unsigned short* l) {
  __builtin_amdgcn_global_load_lds(
      (const __attribute__((address_space(1))) unsigned int*)g,
      (__attribute__((address_space(3))) unsigned int*)l, 16, 0, 0);
}
constexpr int clog2(int v) { return v <= 1 ? 0 : 1 + clog2(v >> 1); }

// ---------------------------------------------------------------------------
// fp32 -> bf16 cast, 8 elems/thread
// ---------------------------------------------------------------------------
__global__ __launch_bounds__(256) void cast_f32_bf16(
    const float* __restrict__ in, unsigned short* __restrict__ out, long n) {
  long i = ((long)blockIdx.x * 256 + threadIdx.x) * 8;
  if (i >= n) return;
  float4 a = *(const float4*)(in + i);
  float4 b = *(const float4*)(in + i + 4);
  ushort4 lo; lo.x = f2bf(a.x); lo.y = f2bf(a.y); lo.z = f2bf(a.z); lo.w = f2bf(a.w);
  ushort4 hi; hi.x = f2bf(b.x); hi.y = f2bf(b.y); hi.z = f2bf(b.z); hi.w = f2bf(b.w);
  *(ushort4*)(out + i) = lo;
  *(ushort4*)(out + i + 4) = hi;
}

// ===========================================================================
// Spatial GEMM v2: 256x256 tile, 512 threads (8 waves 2x4), BK=64, 8-phase
// double-buffered schedule (T3+T4 counted vmcnt + T5 setprio on top of T2).
//
// LDS layout: lds[buf][op(A/B)][khalf][256 rows x 32 k bf16] (64 B rows).
// Stage chunk = 1 KiB = 16 rows x 4 granules(16 B); granule swizzle
//   slot = g ^ ((row>>1)&3)  (bank-conflict-free for ds_read_b128: each
//   16-lane read group covers all 8 16B windows, 2-way alias = free).
// K-half regions die after 2 phases -> phases 3/4 may restage into the
// live buffer. Stage stream per tile t (1 half-tile = 2 gloads/wave/phase):
//   ph1: A_k1(t+1)->buf^1   ph2: B_k1(t+1)->buf^1
//   ph3: A_k0(t+2)->buf     ph4: B_k0(t+2)->buf, then vmcnt(4)+barrier
// vmcnt(4): newest 4 per-wave loads = tile t+2's k0 halves; everything
// tile t+1 needs is older -> complete. Prologue: 6 half-tiles, vmcnt(4).
// Tail staging wraps via &15 (junk into dead regions; keeps counts uniform).
// ===========================================================================
__global__ __launch_bounds__(512, 2) void gemm8_tanh_score(
    const unsigned short* __restrict__ A, const unsigned short* __restrict__ W,
    const float* __restrict__ hvec, const float* __restrict__ wa,
    float* __restrict__ score)
{
  constexpr int BM = 256;
  constexpr int BN = 256;
  __shared__ __align__(16) unsigned short lds[2][2][2][BM * 32];  // 128 KiB
  __shared__ float h_tile[2][BN];
  __shared__ float score_sh[4][BM];

  const int tid  = threadIdx.x;
  const int lane = tid & 63;
  const int wid  = tid >> 6;     // 0..7
  const int wm   = wid >> 2;     // 0..1
  const int wn   = wid & 3;      // 0..3
  const int wr   = wm * 128;
  const int wc   = wn * 64;
  const int l15  = lane & 15;
  const int q    = lane >> 4;
  const int skey = (l15 >> 1) & 3;            // read-side swizzle key
  const int srow = lane >> 2;                 // staging: row within 16-row chunk
  const int sg   = (lane & 3) ^ ((lane >> 3) & 3);  // staging: swizzled granule

  // grid: 1152 blocks = 288 row-tiles x 4 col-tiles; bid%8 -> XCD, col
  // siblings of a row tile co-located (A tile stays in one XCD L2).
  const int bid = blockIdx.x;
  const int rt  = (bid & 7) + (bid >> 5) * 8;
  const int ct  = (bid >> 3) & 3;
  const long r0 = (long)rt * BM;
  const int  c0 = ct * BN;
  const int  b0 = (int)(r0 / (NFRAME * NBOX));
  const int  b1 = (b0 + 1 <= BATCH - 1) ? b0 + 1 : BATCH - 1;
  const int  bnd = (b0 + 1) * (NFRAME * NBOX) - (int)r0;  // rows < bnd -> batch b0

  {
    int s = tid >> 8, i = tid & 255;
    int bb = s ? b1 : b0;
    h_tile[s][i] = hvec[(long)bb * ATTSZ + c0 + i];
  }
  float wac[4];
  #pragma unroll
  for (int j = 0; j < 4; ++j) wac[j] = wa[c0 + wc + j * 16 + l15];

  f32x4 acc[8][4] = {};

  // stage one half-tile (256 rows x 32 k): wave stages chunks 2*wid, 2*wid+1
  auto stage = [&](int buf, int op, int kh, int tile) {
    const unsigned short* src = op ? W : A;
    const long base = op ? (long)c0 : r0;
    #pragma unroll
    for (int cc = 0; cc < 2; ++cc) {
      int chunk = wid * 2 + cc;
      gload_lds16(src + (base + chunk * 16 + srow) * 1024 + tile * 64 + kh * 32 + sg * 8,
                  &lds[buf][op][kh][chunk * 512]);
    }
  };

#define PH(BUF, KS, MH, LOADB, SB, SOP, SKH, STILE, LAST) do {               \
    bf16x8 af_[4];                                                            \
    if (LOADB) {                                                              \
      _Pragma("unroll")                                                       \
      for (int j = 0; j < 4; ++j)                                             \
        bf_[j] = *(const bf16x8*)&lds[BUF][1][KS]                             \
            [(wc + j * 16 + l15) * 32 + ((q ^ skey) * 8)];                    \
    }                                                                         \
    _Pragma("unroll")                                                         \
    for (int i = 0; i < 4; ++i)                                               \
      af_[i] = *(const bf16x8*)&lds[BUF][0][KS]                               \
          [(wr + (MH) * 64 + i * 16 + l15) * 32 + ((q ^ skey) * 8)];          \
    stage(SB, SOP, SKH, STILE);                                               \
    __builtin_amdgcn_s_barrier();                                             \
    __builtin_amdgcn_s_setprio(1);                                            \
    _Pragma("unroll")                                                         \
    for (int i = 0; i < 4; ++i) {                                             \
      _Pragma("unroll")                                                       \
      for (int j = 0; j < 4; ++j)                                             \
        acc[(MH) * 4 + i][j] = __builtin_amdgcn_mfma_f32_16x16x32_bf16(       \
            af_[i], bf_[j], acc[(MH) * 4 + i][j], 0, 0, 0);                   \
    }                                                                         \
    __builtin_amdgcn_s_setprio(0);                                            \
    if (LAST) asm volatile("s_waitcnt vmcnt(4)" ::: "memory");                \
    __builtin_amdgcn_s_barrier();                                             \
  } while (0)

  // prologue: tile0 (4 half-tiles) + tile1 k0 halves; wait leaves 4 in flight
  stage(0, 0, 0, 0); stage(0, 1, 0, 0); stage(0, 0, 1, 0); stage(0, 1, 1, 0);
  stage(1, 0, 0, 1); stage(1, 1, 0, 1);
  asm volatile("s_waitcnt vmcnt(4)" ::: "memory");
  __builtin_amdgcn_s_barrier();

  #pragma unroll 1
  for (int tt = 0; tt < 8; ++tt) {
    const int ta = (2 * tt + 1) & 15;   // t0+1
    const int tb = (2 * tt + 2) & 15;   // t0+2 (= t1+1)
    const int tc = (2 * tt + 3) & 15;   // t1+2
    {
      bf16x8 bf_[4];
      PH(0, 0, 0, true,  1, 0, 1, ta, false);
      PH(0, 0, 1, false, 1, 1, 1, ta, false);
      PH(0, 1, 0, true,  0, 0, 0, tb, false);
      PH(0, 1, 1, false, 0, 1, 0, tb, true);
    }
    {
      bf16x8 bf_[4];
      PH(1, 0, 0, true,  0, 0, 1, tb, false);
      PH(1, 0, 1, false, 0, 1, 1, tb, false);
      PH(1, 1, 0, true,  1, 0, 0, tc, false);
      PH(1, 1, 1, false, 1, 1, 0, tc, true);
    }
  }
#undef PH

  __syncthreads();  // drain + make h_tile visible

  // Epilogue: tanh(acc + h[batch(row)]) * wa, quad-reduce over 16 col-lanes.
  #pragma unroll
  for (int mh = 0; mh < 2; ++mh) {
    #pragma unroll
    for (int i = 0; i < 4; ++i) {
      #pragma unroll
      for (int r = 0; r < 4; ++r) {
        int rowt = wr + mh * 64 + i * 16 + q * 4 + r;
        const float* hrow = h_tile[rowt >= bnd ? 1 : 0];
        float part = 0.f;
        #pragma unroll
        for (int j = 0; j < 4; ++j) {
          float x = acc[mh * 4 + i][j][r] + hrow[wc + j * 16 + l15];
          part += fast_tanh(x) * wac[j];
        }
        part += __shfl_xor(part, 1); part += __shfl_xor(part, 2);
        part += __shfl_xor(part, 4); part += __shfl_xor(part, 8);
        if (l15 == 0) score_sh[wn][rowt] = part;
      }
    }
  }
  __syncthreads();
  if (tid < BM)
    atomicAdd(score + r0 + tid,
              score_sh[0][tid] + score_sh[1][tid] + score_sh[2][tid] + score_sh[3][tid]);
}

// ---------------------------------------------------------------------------
// Templated bf16 GEMM + tanh + row-score reduction (kept for the temporal
// pass: K=3072 not a power of two, M small -> old structure still best fit).
// ---------------------------------------------------------------------------
template<int TM, int TN, bool LINGRID, int NCOLT>
__global__ __launch_bounds__(256, 3) void gemm_tanh_score(
    const unsigned short* __restrict__ A, const unsigned short* __restrict__ W,
    const float* __restrict__ hvec, const float* __restrict__ wa,
    float* __restrict__ score, int K, int rows_per_b)
{
  constexpr int BM = 2 * TM * 16;
  constexpr int BN = 2 * TN * 16;
  __shared__ __align__(16) unsigned short ldsA[BM * 64];
  __shared__ __align__(16) unsigned short ldsW[BN * 64];
  __shared__ float h_tile[BN];
  __shared__ float score_sh[2][BM];

  const int tid  = threadIdx.x;
  const int lane = tid & 63;
  const int wid  = tid >> 6;
  const int wr   = (wid >> 1) * (TM * 16);
  const int wc   = (wid & 1) * (TN * 16);
  const int l15  = lane & 15;
  const int q    = lane >> 4;
  const int rl   = l15 & 7;            // fragment-read swizzle key
  const int srow = lane >> 3;          // staging: row within 8-row chunk
  const int sgr  = (lane & 7) ^ srow;  // staging: swizzled source granule

  long r0; int c0;
  if (LINGRID) {
    int bid = blockIdx.x;
    int rt = (bid & 7) + (bid >> (3 + clog2(NCOLT))) * 8;
    int ct = (bid >> 3) & (NCOLT - 1);
    r0 = (long)rt * BM; c0 = ct * BN;
  } else {
    r0 = (long)blockIdx.y * BM; c0 = blockIdx.x * BN;
  }
  const int b0 = (int)(r0 / rows_per_b);   // tile lies in one batch

  for (int i = tid; i < BN; i += 256)
    h_tile[i] = hvec[(long)b0 * ATTSZ + c0 + i];
  float wac[TN];
  #pragma unroll
  for (int j = 0; j < TN; ++j) wac[j] = wa[c0 + wc + j * 16 + l15];

  f32x4 acc[TM][TN] = {};

  for (int k0 = 0; k0 < K; k0 += 64) {
    __syncthreads();
    #pragma unroll
    for (int it = 0; it < BM / 32; ++it) {
      int c = wid * (BM / 32) + it;
      gload_lds16(A + (r0 + c * 8 + srow) * (long)K + k0 + (sgr << 3), ldsA + c * 512);
    }
    #pragma unroll
    for (int it = 0; it < BN / 32; ++it) {
      int c = wid * (BN / 32) + it;
      gload_lds16(W + ((long)(c0 + c * 8 + srow)) * K + k0 + (sgr << 3), ldsW + c * 512);
    }
    __syncthreads();
    #pragma unroll
    for (int s = 0; s < 2; ++s) {
      bf16x8 af[TM], wf[TN];
      const int gsw = ((s * 4 + q) ^ rl) << 3;    // swizzled granule offset
      #pragma unroll
      for (int i = 0; i < TM; ++i)
        af[i] = *(const bf16x8*)(ldsA + (wr + i * 16 + l15) * 64 + gsw);
      #pragma unroll
      for (int j = 0; j < TN; ++j)
        wf[j] = *(const bf16x8*)(ldsW + (wc + j * 16 + l15) * 64 + gsw);
      #pragma unroll
      for (int i = 0; i < TM; ++i)
        #pragma unroll
        for (int j = 0; j < TN; ++j)
          acc[i][j] = __builtin_amdgcn_mfma_f32_16x16x32_bf16(af[i], wf[j], acc[i][j], 0, 0, 0);
    }
  }

  // Epilogue: tanh(acc + h) * wa, quad-reduce over the 16 col-lanes.
  #pragma unroll
  for (int i = 0; i < TM; ++i) {
    #pragma unroll
    for (int r = 0; r < 4; ++r) {
      float part = 0.f;
      #pragma unroll
      for (int j = 0; j < TN; ++j) {
        float x = acc[i][j][r] + h_tile[wc + j * 16 + l15];
        part += fast_tanh(x) * wac[j];
      }
      part += __shfl_xor(part, 1); part += __shfl_xor(part, 2);
      part += __shfl_xor(part, 4); part += __shfl_xor(part, 8);
      if (l15 == 0) score_sh[wid & 1][wr + i * 16 + q * 4 + r] = part;
    }
  }
  __syncthreads();
  if (tid < BM)
    atomicAdd(score + r0 + tid, score_sh[0][tid] + score_sh[1][tid]);
}

// ---------------------------------------------------------------------------
// h projections (biases folded)
// ---------------------------------------------------------------------------
__global__ __launch_bounds__(256) void hidden_proj(
    const float* __restrict__ hidden,
    const float* __restrict__ s_wh_w, const float* __restrict__ s_wh_b,
    const float* __restrict__ s_wv_b,
    const float* __restrict__ t_wh_w, const float* __restrict__ t_wh_b,
    const float* __restrict__ t_wv_b,
    float* __restrict__ h_s, float* __restrict__ h_t)
{
  const float *W, *b1, *b2;
  float* out;
  if (blockIdx.y == 0) { W = s_wh_w; b1 = s_wh_b; b2 = s_wv_b; out = h_s; }
  else                 { W = t_wh_w; b1 = t_wh_b; b2 = t_wv_b; out = h_t; }
  const int lane = threadIdx.x & 63;
  const int wid  = threadIdx.x >> 6;
  const int a    = blockIdx.x * 4 + wid;
  __shared__ float hs[64 * 256];
  float acc[64];
  #pragma unroll
  for (int b = 0; b < 64; ++b) acc[b] = 0.f;

  for (int dc = 0; dc < 4; ++dc) {
    __syncthreads();
    for (int i = threadIdx.x; i < 4096; i += 256) {
      int b = i >> 6, d4 = i & 63;
      *(float4*)(hs + b * 256 + d4 * 4) =
          *(const float4*)(hidden + b * 1024 + dc * 256 + d4 * 4);
    }
    __syncthreads();
    float4 w4 = *(const float4*)(W + (long)a * 1024 + dc * 256 + lane * 4);
    #pragma unroll
    for (int b = 0; b < 64; ++b) {
      float4 h4 = *(const float4*)(hs + b * 256 + lane * 4);
      acc[b] += w4.x * h4.x + w4.y * h4.y + w4.z * h4.z + w4.w * h4.w;
    }
  }
  #pragma unroll
  for (int b = 0; b < 64; ++b) {
    #pragma unroll
    for (int off = 1; off < 64; off <<= 1)
      acc[b] += __shfl_xor(acc[b], off);
  }
  float res = 0.f;
  #pragma unroll
  for (int b = 0; b < 64; ++b)
    if (lane == b) res = acc[b];
  out[lane * 1024 + a] = res + b1[a] + b2[a];
}

// ---------------------------------------------------------------------------
// Spatial softmax + weighted sum (bf16 obj) -> feat fp32 + feat bf16
// ---------------------------------------------------------------------------
__global__ __launch_bounds__(256) void spatial_softmax_obj_bf16(
    const unsigned short* __restrict__ objb, const float* __restrict__ score,
    const float* __restrict__ frame, float* __restrict__ feat,
    unsigned short* __restrict__ featb)
{
  const int bf = blockIdx.x;
  __shared__ float alpha[NBOX];
  if (threadIdx.x < 64) {
    int n = threadIdx.x;
    float v = (n < NBOX) ? score[bf * NBOX + n] : -1e30f;
    float m = v;
    #pragma unroll
    for (int off = 32; off; off >>= 1) m = fmaxf(m, __shfl_xor(m, off));
    float e = (n < NBOX) ? __expf(v - m) : 0.f;
    float ssum = e;
    #pragma unroll
    for (int off = 32; off; off >>= 1) ssum += __shfl_xor(ssum, off);
    if (n < NBOX) alpha[n] = e / ssum;
  }
  __syncthreads();
  const unsigned short* base = objb + (long)bf * NBOX * REGION;
  float4 av = {0.f, 0.f, 0.f, 0.f};
  #pragma unroll 4
  for (int n = 0; n < NBOX; ++n) {
    float al = alpha[n];
    ushort4 o = *(const ushort4*)(base + n * REGION + threadIdx.x * 4);
    av.x += al * bf2f(o.x); av.y += al * bf2f(o.y);
    av.z += al * bf2f(o.z); av.w += al * bf2f(o.w);
  }
  float* frow = feat + (long)bf * FEAT2;
  unsigned short* fbrow = featb + (long)bf * FEAT2;
  *(float4*)(frow + threadIdx.x * 4) = av;
  ushort4 avb; avb.x = f2bf(av.x); avb.y = f2bf(av.y); avb.z = f2bf(av.z); avb.w = f2bf(av.w);
  *(ushort4*)(fbrow + threadIdx.x * 4) = avb;
  const float* fsrc = frame + (long)bf * 2 * HIDDEN;
  #pragma unroll
  for (int c = 0; c < 2; ++c) {
    float4 v = *(const float4*)(fsrc + (threadIdx.x + c * 256) * 4);
    *(float4*)(frow + REGION + (threadIdx.x + c * 256) * 4) = v;
    ushort4 vb; vb.x = f2bf(v.x); vb.y = f2bf(v.y); vb.z = f2bf(v.z); vb.w = f2bf(v.w);
    *(ushort4*)(fbrow + REGION + (threadIdx.x + c * 256) * 4) = vb;
  }
}

// ---------------------------------------------------------------------------
// Temporal softmax + weighted sum of fp32 feat -> out[B, 3072]
// ---------------------------------------------------------------------------
__global__ __launch_bounds__(256) void temporal_out(
    const float* __restrict__ score2, const float* __restrict__ feat,
    float* __restrict__ out)
{
  const int b = blockIdx.x;
  __shared__ float beta[NFRAME];
  if (threadIdx.x < 64) {
    int f = threadIdx.x;
    float v = (f < NFRAME) ? score2[b * NFRAME + f] : -1e30f;
    float m = v;
    #pragma unroll
    for (int off = 32; off; off >>= 1) m = fmaxf(m, __shfl_xor(m, off));
    float e = (f < NFRAME) ? __expf(v - m) : 0.f;
    float ssum = e;
    #pragma unroll
    for (int off = 32; off; off >>= 1) ssum += __shfl_xor(ssum, off);
    if (f < NFRAME) beta[f] = e / ssum;
  }
  __syncthreads();
  int col = blockIdx.y * 1024 + threadIdx.x * 4;
  float4 av = {0.f, 0.f, 0.f, 0.f};
  #pragma unroll 4
  for (int f = 0; f < NFRAME; ++f) {
    float bw = beta[f];
    float4 v = *(const float4*)(feat + (long)(b * NFRAME + f) * FEAT2 + col);
    av.x += bw * v.x; av.y += bw * v.y; av.z += bw * v.z; av.w += bw * v.w;
  }
  *(float4*)(out + (long)b * FEAT2 + col) = av;
}

// ===========================================================================
// Fallback path (fp32 inputs, inline conversion) — only if ws too small.
// ===========================================================================
#define FBM 128
#define FBN 128
#define FBK 64
#define LDKP 72
__global__ __launch_bounds__(256) void fused_gemm_tanh_score_f32(
    const float* __restrict__ A, const float* __restrict__ W,
    const float* __restrict__ hvec, const float* __restrict__ wa,
    float* __restrict__ score, int M, int K, int rows_per_b)
{
  __shared__ unsigned short ldsA[FBM * LDKP];
  __shared__ unsigned short ldsW[FBN * LDKP];
  const int tid  = threadIdx.x;
  const int lane = tid & 63;
  const int wid  = tid >> 6;
  const int wr   = (wid >> 1) * 64;
  const int wc   = (wid & 1) * 64;
  const int l15  = lane & 15;
  const int q    = lane >> 4;
  const long r0  = (long)blockIdx.y * FBM;
  const int  c0  = blockIdx.x * FBN;

  f32x4 acc[4][4] = {};
  for (int k0 = 0; k0 < K; k0 += FBK) {
    __syncthreads();
    #pragma unroll
    for (int it = 0; it < 8; ++it) {
      int c = tid + it * 256;
      int row = c >> 4, qb = c & 15;
      float4 s = *(const float4*)(A + (r0 + row) * (long)K + k0 + qb * 4);
      ushort4 d; d.x = f2bf(s.x); d.y = f2bf(s.y); d.z = f2bf(s.z); d.w = f2bf(s.w);
      *(ushort4*)(ldsA + row * LDKP + qb * 4) = d;
    }
    #pragma unroll
    for (int it = 0; it < 8; ++it) {
      int c = tid + it * 256;
      int row = c >> 4, qb = c & 15;
      float4 s = *(const float4*)(W + (c0 + row) * (long)K + k0 + qb * 4);
      ushort4 d; d.x = f2bf(s.x); d.y = f2bf(s.y); d.z = f2bf(s.z); d.w = f2bf(s.w);
      *(ushort4*)(ldsW + row * LDKP + qb * 4) = d;
    }
    __syncthreads();
    #pragma unroll
    for (int s = 0; s < 2; ++s) {
      bf16x8 af[4], bfr[4];
      #pragma unroll
      for (int i = 0; i < 4; ++i)
        af[i] = *(const bf16x8*)(ldsA + (wr + i * 16 + l15) * LDKP + s * 32 + q * 8);
      #pragma unroll
      for (int j = 0; j < 4; ++j)
        bfr[j] = *(const bf16x8*)(ldsW + (wc + j * 16 + l15) * LDKP + s * 32 + q * 8);
      #pragma unroll
      for (int i = 0; i < 4; ++i)
        #pragma unroll
        for (int j = 0; j < 4; ++j)
          acc[i][j] = __builtin_amdgcn_mfma_f32_16x16x32_bf16(af[i], bfr[j], acc[i][j], 0, 0, 0);
    }
  }
  float wac[4];
  #pragma unroll
  for (int j = 0; j < 4; ++j) wac[j] = wa[c0 + wc + j * 16 + l15];
  #pragma unroll
  for (int i = 0; i < 4; ++i) {
    #pragma unroll
    for (int r = 0; r < 4; ++r) {
      int row = (int)r0 + wr + i * 16 + q * 4 + r;
      const float* hrow = hvec + (long)(row / rows_per_b) * ATTSZ;
      float part = 0.f;
      #pragma unroll
      for (int j = 0; j < 4; ++j) {
        float x = acc[i][j][r] + hrow[c0 + wc + j * 16 + l15];
        part += fast_tanh(x) * wac[j];
      }
      part += __shfl_xor(part, 1); part += __shfl_xor(part, 2);
      part += __shfl_xor(part, 4); part += __shfl_xor(part, 8);
      if (l15 == 0) atomicAdd(score + row, part);
    }
  }
}

__global__ __launch_bounds__(256) void spatial_softmax_obj_f32(
    const float* __restrict__ obj, const float* __restrict__ score,
    const float* __restrict__ frame, float* __restrict__ feat)
{
  const int bf = blockIdx.x;
  __shared__ float alpha[NBOX];
  if (threadIdx.x < 64) {
    int n = threadIdx.x;
    float v = (n < NBOX) ? score[bf * NBOX + n] : -1e30f;
    float m = v;
    #pragma unroll
    for (int off = 32; off; off >>= 1) m = fmaxf(m, __shfl_xor(m, off));
    float e = (n < NBOX) ? __expf(v - m) : 0.f;
    float ssum = e;
    #pragma unroll
    for (int off = 32; off; off >>= 1) ssum += __shfl_xor(ssum, off);
    if (n < NBOX) alpha[n] = e / ssum;
  }
  __syncthreads();
  const float* base = obj + (long)bf * NBOX * REGION;
  float4 av = {0.f, 0.f, 0.f, 0.f};
  for (int n = 0; n < NBOX; ++n) {
    float al = alpha[n];
    float4 o = *(const float4*)(base + n * REGION + threadIdx.x * 4);
    av.x += al * o.x; av.y += al * o.y; av.z += al * o.z; av.w += al * o.w;
  }
  float* frow = feat + (long)bf * FEAT2;
  *(float4*)(frow + threadIdx.x * 4) = av;
  const float4* fsrc = (const float4*)(frame + (long)bf * 2 * HIDDEN);
  float4* fdst = (float4*)(frow + REGION);
  fdst[threadIdx.x]       = fsrc[threadIdx.x];
  fdst[threadIdx.x + 256] = fsrc[threadIdx.x + 256];
}

__global__ __launch_bounds__(256) void temporal_out_f32(
    const float* __restrict__ score2, const float* __restrict__ feat,
    float* __restrict__ out)
{
  const int b = blockIdx.x;
  __shared__ float beta[NFRAME];
  if (threadIdx.x < 64) {
    int f = threadIdx.x;
    float v = (f < NFRAME) ? score2[b * NFRAME + f] : -1e30f;
    float m = v;
    #pragma unroll
    for (int off = 32; off; off >>= 1) m = fmaxf(m, __shfl_xor(m, off));
    float e = (f < NFRAME) ? __expf(v - m) : 0.f;
    float ssum = e;
    #pragma unroll
    for (int off = 32; off; off >>= 1) ssum += __shfl_xor(ssum, off);
    if (f < NFRAME) beta[f] = e / ssum;
  }
  __syncthreads();
  #pragma unroll
  for (int c = 0; c < 3; ++c) {
    int col = (threadIdx.x + c * 256) * 4;
    float4 av = {0.f, 0.f, 0.f, 0.f};
    for (int f = 0; f < NFRAME; ++f) {
      float bw = beta[f];
      float4 v = *(const float4*)(feat + (long)(b * NFRAME + f) * FEAT2 + col);
      av.x += bw * v.x; av.y += bw * v.y; av.z += bw * v.z; av.w += bw * v.w;
    }
    *(float4*)(out + (long)b * FEAT2 + col) = av;
  }
}

// ---------------------------------------------------------------------------
extern "C" void kernel_launch(void* const* d_in, const int* in_sizes, int n_in,
                              void* d_out, int out_size, void* d_ws, size_t ws_size,
                              hipStream_t stream) {
  const float* frame  = (const float*)d_in[0];
  const float* obj    = (const float*)d_in[1];
  const float* hidden = (const float*)d_in[2];
  const float* s_wh_w = (const float*)d_in[3];
  const float* s_wh_b = (const float*)d_in[4];
  const float* s_wv_w = (const float*)d_in[5];
  const float* s_wv_b = (const float*)d_in[6];
  const float* s_wa_w = (const float*)d_in[7];
  const float* t_wh_w = (const float*)d_in[8];
  const float* t_wh_b = (const float*)d_in[9];
  const float* t_wv_w = (const float*)d_in[10];
  const float* t_wv_b = (const float*)d_in[11];
  const float* t_wa_w = (const float*)d_in[12];
  float* out = (float*)d_out;

  char* p = (char*)d_ws;
  auto alloc = [&](size_t bytes) { char* r = p; p += (bytes + 255) & ~255ull; return r; };
  float* h_s     = (float*)alloc(65536 * 4);
  float* h_t     = (float*)alloc(65536 * 4);
  float* score_s = (float*)alloc((size_t)M_S * 4);   // contiguous with score2
  float* score2  = (float*)alloc((size_t)M_T * 4);
  float* feat    = (float*)alloc((size_t)M_T * FEAT2 * 4);
  unsigned short* objb  = (unsigned short*)alloc((size_t)M_S * REGION * 2);
  unsigned short* featb = (unsigned short*)alloc((size_t)M_T * FEAT2 * 2);
  unsigned short* wvsb  = (unsigned short*)alloc((size_t)ATTSZ * REGION * 2);
  unsigned short* wvtb  = (unsigned short*)alloc((size_t)HIDDEN * FEAT2 * 2);
  size_t needed = (size_t)(p - (char*)d_ws);
  bool fast = needed <= ws_size;

  hipMemsetAsync(score_s, 0, (size_t)(M_S + M_T) * sizeof(float), stream);
  hidden_proj<<<dim3(256, 2), 256, 0, stream>>>(
      hidden, s_wh_w, s_wh_b, s_wv_b, t_wh_w, t_wh_b, t_wv_b, h_s, h_t);

  if (fast) {
    cast_f32_bf16<<<(M_S * (long)REGION) / 2048, 256, 0, stream>>>(obj, objb, (long)M_S * REGION);
    cast_f32_bf16<<<(ATTSZ * (long)REGION) / 2048, 256, 0, stream>>>(s_wv_w, wvsb, (long)ATTSZ * REGION);
    cast_f32_bf16<<<(HIDDEN * (long)FEAT2) / 2048, 256, 0, stream>>>(t_wv_w, wvtb, (long)HIDDEN * FEAT2);

    // Spatial: 256x256 tiles, 8-phase pipelined, 1152 blocks (288 rt x 4 ct),
    // XCD-swizzled (1152 % 8 == 0 -> bijective).
    gemm8_tanh_score<<<dim3(8 * (M_S / 256) / 2), 512, 0, stream>>>(
        objb, wvsb, h_s, s_wa_w, score_s);

    spatial_softmax_obj_bf16<<<M_T, 256, 0, stream>>>(objb, score_s, frame, feat, featb);

    // Temporal: 32x128 tiles, grid (8, 64) = 512 blocks.
    gemm_tanh_score<1, 4, false, 8><<<dim3(8, M_T / 32), 256, 0, stream>>>(
        featb, wvtb, h_t, t_wa_w, score2, FEAT2, NFRAME);

    temporal_out<<<dim3(BATCH, 3), 256, 0, stream>>>(score2, feat, out);
  } else {
    fused_gemm_tanh_score_f32<<<dim3(8, M_S / FBM), 256, 0, stream>>>(
        obj, s_wv_w, h_s, s_wa_w, score_s, M_S, REGION, NFRAME * NBOX);
    spatial_softmax_obj_f32<<<M_T, 256, 0, stream>>>(obj, score_s, frame, feat);
    fused_gemm_tanh_score_f32<<<dim3(8, M_T / FBM), 256, 0, stream>>>(
        feat, t_wv_w, h_t, t_wa_w, score2, M_T, FEAT2, NFRAME);
    temporal_out_f32<<<BATCH, 256, 0, stream>>>(score2, feat, out);
  }
}

// Round 2
// 733.104 us; speedup vs baseline: 1.0731x; 1.0731x over previous
//
#include <hip/hip_runtime.h>
#include <hip/hip_bf16.h>
#include <stdint.h>

#define BATCH  64
#define NFRAME 32
#define NBOX   36
#define REGION 1024
#define HIDDEN 1024
#define ATTSZ  1024
#define FEAT2  3072
#define M_S (BATCH * NFRAME * NBOX)   // 73728
#define M_T (BATCH * NFRAME)          // 2048

typedef __attribute__((ext_vector_type(8))) short bf16x8;
typedef __attribute__((ext_vector_type(4))) float f32x4;

__device__ __forceinline__ unsigned short f2bf(float f) {
  union { float f; uint32_t u; } v; v.f = f;
  return (unsigned short)((v.u + 0x7FFFu + ((v.u >> 16) & 1u)) >> 16);  // RNE
}
__device__ __forceinline__ float bf2f(unsigned short u) {
  union { uint32_t u; float f; } v; v.u = (uint32_t)u << 16; return v.f;
}
__device__ __forceinline__ float fast_tanh(float x) {
  float e = __expf(2.f * x);
  return 1.f - 2.f / (e + 1.f);
}
__device__ __forceinline__ void gload_lds16(const unsigned short* g, unsigned short* l) {
  __builtin_amdgcn_global_load_lds(
      (const __attribute__((address_space(1))) unsigned int*)g,
      (__attribute__((address_space(3))) unsigned int*)l, 16, 0, 0);
}
constexpr int clog2(int v) { return v <= 1 ? 0 : 1 + clog2(v >> 1); }

// ---------------------------------------------------------------------------
// Merged prep kernel: obj cast + score memset + weight casts in ONE launch.
// R2 experiment: 9 -> 6 graph nodes to test the launch-boundary hypothesis
// (kernel-sum estimate ~215us of the 543us non-spatial-gemm budget; if the
// rest is per-node overhead, removing 3 boundaries should show up directly).
// Segments by blockIdx.x: [obj cast 36864 | memset 74 | wvs 512 | wvt 1536].
// Cast body is bit-identical to the old cast_f32_bf16 (8 elems/thread).
// ---------------------------------------------------------------------------
__device__ __forceinline__ void cast8(const float* __restrict__ in,
                                      unsigned short* __restrict__ out, int bid) {
  long i = ((long)bid * 256 + threadIdx.x) * 8;
  float4 a = *(const float4*)(in + i);
  float4 b = *(const float4*)(in + i + 4);
  ushort4 lo; lo.x = f2bf(a.x); lo.y = f2bf(a.y); lo.z = f2bf(a.z); lo.w = f2bf(a.w);
  ushort4 hi; hi.x = f2bf(b.x); hi.y = f2bf(b.y); hi.z = f2bf(b.z); hi.w = f2bf(b.w);
  *(ushort4*)(out + i) = lo;
  *(ushort4*)(out + i + 4) = hi;
}

#define PREP_OBJ_BLKS  (M_S * REGION / 2048)          // 36864
#define PREP_MS_BLKS   ((M_S + M_T) / 1024)           // 74 (exact: 75776/1024)
#define PREP_WVS_BLKS  (ATTSZ * REGION / 2048)        // 512
#define PREP_WVT_BLKS  (HIDDEN * FEAT2 / 2048)        // 1536
#define PREP_BLKS (PREP_OBJ_BLKS + PREP_MS_BLKS + PREP_WVS_BLKS + PREP_WVT_BLKS)

__global__ __launch_bounds__(256) void prep(
    const float* __restrict__ obj, unsigned short* __restrict__ objb,
    const float* __restrict__ wvs, unsigned short* __restrict__ wvsb,
    const float* __restrict__ wvt, unsigned short* __restrict__ wvtb,
    float* __restrict__ score_zero)
{
  int bid = blockIdx.x;
  if (bid < PREP_OBJ_BLKS) { cast8(obj, objb, bid); return; }
  bid -= PREP_OBJ_BLKS;
  if (bid < PREP_MS_BLKS) {
    int i = (bid * 256 + threadIdx.x) * 4;             // 74*1024 = 75776 exact
    float4 z = {0.f, 0.f, 0.f, 0.f};
    *(float4*)(score_zero + i) = z;
    return;
  }
  bid -= PREP_MS_BLKS;
  if (bid < PREP_WVS_BLKS) { cast8(wvs, wvsb, bid); return; }
  bid -= PREP_WVS_BLKS;
  cast8(wvt, wvtb, bid);
}

// ---------------------------------------------------------------------------
// Templated bf16 GEMM + tanh + row-score reduction.  (Proven R0 version:
// 193us / 800 TF on the spatial shape.  R1's 8-phase 256^2 rewrite REGRESSED
// to 242us / MfmaUtil 27% — 1 block/CU killed inter-block TLP, pipeline only
// 2 half-tiles deep vs m201's 3, 4.5 serial blocks/CU of un-overlapped
// prologue/epilogue.  Reverted; do not re-attempt without the exact m201
// schedule.)
//   score[row] += sum_col tanh( (A @ W^T)[row][col] + h[b(row)][col] ) * wa[col]
// Block = 256 threads = 4 waves in 2x2; wave tile (TM*16) x (TN*16);
// block tile BM x BN, BK=64, global_load_lds staging.
// LDS XOR-swizzle: chunk = 8 rows x 8 granules(16B); slot (r,p) holds logical
// granule p^r -> conflict-free reads without padding (measured: 4.2e7 -> 0).
// LINGRID: bid%8 selects XCD; col-siblings placed 8 apart so a row-tile's A
// lives in ONE XCD L2 (measured: FETCH 305->107 MB).
// __launch_bounds__(256,3): cap regs ~170 so 3 blocks/CU co-reside.
// REQUIRES: BM-aligned row tiles within one batch.
// ---------------------------------------------------------------------------
template<int TM, int TN, bool LINGRID, int NCOLT>
__global__ __launch_bounds__(256, 3) void gemm_tanh_score(
    const unsigned short* __restrict__ A, const unsigned short* __restrict__ W,
    const float* __restrict__ hvec, const float* __restrict__ wa,
    float* __restrict__ score, int K, int rows_per_b)
{
  constexpr int BM = 2 * TM * 16;
  constexpr int BN = 2 * TN * 16;
  __shared__ __align__(16) unsigned short ldsA[BM * 64];
  __shared__ __align__(16) unsigned short ldsW[BN * 64];
  __shared__ float h_tile[BN];
  __shared__ float score_sh[2][BM];

  const int tid  = threadIdx.x;
  const int lane = tid & 63;
  const int wid  = tid >> 6;
  const int wr   = (wid >> 1) * (TM * 16);
  const int wc   = (wid & 1) * (TN * 16);
  const int l15  = lane & 15;
  const int q    = lane >> 4;
  const int rl   = l15 & 7;            // fragment-read swizzle key
  const int srow = lane >> 3;          // staging: row within 8-row chunk
  const int sgr  = (lane & 7) ^ srow;  // staging: swizzled source granule

  long r0; int c0;
  if (LINGRID) {
    int bid = blockIdx.x;
    int rt = (bid & 7) + (bid >> (3 + clog2(NCOLT))) * 8;
    int ct = (bid >> 3) & (NCOLT - 1);
    r0 = (long)rt * BM; c0 = ct * BN;
  } else {
    r0 = (long)blockIdx.y * BM; c0 = blockIdx.x * BN;
  }
  const int b0 = (int)(r0 / rows_per_b);   // tile lies in one batch

  for (int i = tid; i < BN; i += 256)
    h_tile[i] = hvec[(long)b0 * ATTSZ + c0 + i];
  float wac[TN];
  #pragma unroll
  for (int j = 0; j < TN; ++j) wac[j] = wa[c0 + wc + j * 16 + l15];

  f32x4 acc[TM][TN] = {};

  for (int k0 = 0; k0 < K; k0 += 64) {
    __syncthreads();
    #pragma unroll
    for (int it = 0; it < BM / 32; ++it) {
      int c = wid * (BM / 32) + it;
      gload_lds16(A + (r0 + c * 8 + srow) * (long)K + k0 + (sgr << 3), ldsA + c * 512);
    }
    #pragma unroll
    for (int it = 0; it < BN / 32; ++it) {
      int c = wid * (BN / 32) + it;
      gload_lds16(W + ((long)(c0 + c * 8 + srow)) * K + k0 + (sgr << 3), ldsW + c * 512);
    }
    __syncthreads();
    #pragma unroll
    for (int s = 0; s < 2; ++s) {
      bf16x8 af[TM], wf[TN];
      const int gsw = ((s * 4 + q) ^ rl) << 3;    // swizzled granule offset
      #pragma unroll
      for (int i = 0; i < TM; ++i)
        af[i] = *(const bf16x8*)(ldsA + (wr + i * 16 + l15) * 64 + gsw);
      #pragma unroll
      for (int j = 0; j < TN; ++j)
        wf[j] = *(const bf16x8*)(ldsW + (wc + j * 16 + l15) * 64 + gsw);
      #pragma unroll
      for (int i = 0; i < TM; ++i)
        #pragma unroll
        for (int j = 0; j < TN; ++j)
          acc[i][j] = __builtin_amdgcn_mfma_f32_16x16x32_bf16(af[i], wf[j], acc[i][j], 0, 0, 0);
    }
  }

  // Epilogue: tanh(acc + h) * wa, quad-reduce over the 16 col-lanes.
  #pragma unroll
  for (int i = 0; i < TM; ++i) {
    #pragma unroll
    for (int r = 0; r < 4; ++r) {
      float part = 0.f;
      #pragma unroll
      for (int j = 0; j < TN; ++j) {
        float x = acc[i][j][r] + h_tile[wc + j * 16 + l15];
        part += fast_tanh(x) * wac[j];
      }
      part += __shfl_xor(part, 1); part += __shfl_xor(part, 2);
      part += __shfl_xor(part, 4); part += __shfl_xor(part, 8);
      if (l15 == 0) score_sh[wid & 1][wr + i * 16 + q * 4 + r] = part;
    }
  }
  __syncthreads();
  if (tid < BM)
    atomicAdd(score + r0 + tid, score_sh[0][tid] + score_sh[1][tid]);
}

// ---------------------------------------------------------------------------
// h projections (biases folded)
// ---------------------------------------------------------------------------
__global__ __launch_bounds__(256) void hidden_proj(
    const float* __restrict__ hidden,
    const float* __restrict__ s_wh_w, const float* __restrict__ s_wh_b,
    const float* __restrict__ s_wv_b,
    const float* __restrict__ t_wh_w, const float* __restrict__ t_wh_b,
    const float* __restrict__ t_wv_b,
    float* __restrict__ h_s, float* __restrict__ h_t)
{
  const float *W, *b1, *b2;
  float* out;
  if (blockIdx.y == 0) { W = s_wh_w; b1 = s_wh_b; b2 = s_wv_b; out = h_s; }
  else                 { W = t_wh_w; b1 = t_wh_b; b2 = t_wv_b; out = h_t; }
  const int lane = threadIdx.x & 63;
  const int wid  = threadIdx.x >> 6;
  const int a    = blockIdx.x * 4 + wid;
  __shared__ float hs[64 * 256];
  float acc[64];
  #pragma unroll
  for (int b = 0; b < 64; ++b) acc[b] = 0.f;

  for (int dc = 0; dc < 4; ++dc) {
    __syncthreads();
    for (int i = threadIdx.x; i < 4096; i += 256) {
      int b = i >> 6, d4 = i & 63;
      *(float4*)(hs + b * 256 + d4 * 4) =
          *(const float4*)(hidden + b * 1024 + dc * 256 + d4 * 4);
    }
    __syncthreads();
    float4 w4 = *(const float4*)(W + (long)a * 1024 + dc * 256 + lane * 4);
    #pragma unroll
    for (int b = 0; b < 64; ++b) {
      float4 h4 = *(const float4*)(hs + b * 256 + lane * 4);
      acc[b] += w4.x * h4.x + w4.y * h4.y + w4.z * h4.z + w4.w * h4.w;
    }
  }
  #pragma unroll
  for (int b = 0; b < 64; ++b) {
    #pragma unroll
    for (int off = 1; off < 64; off <<= 1)
      acc[b] += __shfl_xor(acc[b], off);
  }
  float res = 0.f;
  #pragma unroll
  for (int b = 0; b < 64; ++b)
    if (lane == b) res = acc[b];
  out[lane * 1024 + a] = res + b1[a] + b2[a];
}

// ---------------------------------------------------------------------------
// Spatial softmax + weighted sum (bf16 obj) -> feat fp32 + feat bf16
// ---------------------------------------------------------------------------
__global__ __launch_bounds__(256) void spatial_softmax_obj_bf16(
    const unsigned short* __restrict__ objb, const float* __restrict__ score,
    const float* __restrict__ frame, float* __restrict__ feat,
    unsigned short* __restrict__ featb)
{
  const int bf = blockIdx.x;
  __shared__ float alpha[NBOX];
  if (threadIdx.x < 64) {
    int n = threadIdx.x;
    float v = (n < NBOX) ? score[bf * NBOX + n] : -1e30f;
    float m = v;
    #pragma unroll
    for (int off = 32; off; off >>= 1) m = fmaxf(m, __shfl_xor(m, off));
    float e = (n < NBOX) ? __expf(v - m) : 0.f;
    float ssum = e;
    #pragma unroll
    for (int off = 32; off; off >>= 1) ssum += __shfl_xor(ssum, off);
    if (n < NBOX) alpha[n] = e / ssum;
  }
  __syncthreads();
  const unsigned short* base = objb + (long)bf * NBOX * REGION;
  float4 av = {0.f, 0.f, 0.f, 0.f};
  #pragma unroll 4
  for (int n = 0; n < NBOX; ++n) {
    float al = alpha[n];
    ushort4 o = *(const ushort4*)(base + n * REGION + threadIdx.x * 4);
    av.x += al * bf2f(o.x); av.y += al * bf2f(o.y);
    av.z += al * bf2f(o.z); av.w += al * bf2f(o.w);
  }
  float* frow = feat + (long)bf * FEAT2;
  unsigned short* fbrow = featb + (long)bf * FEAT2;
  *(float4*)(frow + threadIdx.x * 4) = av;
  ushort4 avb; avb.x = f2bf(av.x); avb.y = f2bf(av.y); avb.z = f2bf(av.z); avb.w = f2bf(av.w);
  *(ushort4*)(fbrow + threadIdx.x * 4) = avb;
  const float* fsrc = frame + (long)bf * 2 * HIDDEN;
  #pragma unroll
  for (int c = 0; c < 2; ++c) {
    float4 v = *(const float4*)(fsrc + (threadIdx.x + c * 256) * 4);
    *(float4*)(frow + REGION + (threadIdx.x + c * 256) * 4) = v;
    ushort4 vb; vb.x = f2bf(v.x); vb.y = f2bf(v.y); vb.z = f2bf(v.z); vb.w = f2bf(v.w);
    *(ushort4*)(fbrow + REGION + (threadIdx.x + c * 256) * 4) = vb;
  }
}

// ---------------------------------------------------------------------------
// Temporal softmax + weighted sum of fp32 feat -> out[B, 3072]
// grid (64, 3): blockIdx.y picks a 1024-col chunk.
// ---------------------------------------------------------------------------
__global__ __launch_bounds__(256) void temporal_out(
    const float* __restrict__ score2, const float* __restrict__ feat,
    float* __restrict__ out)
{
  const int b = blockIdx.x;
  __shared__ float beta[NFRAME];
  if (threadIdx.x < 64) {
    int f = threadIdx.x;
    float v = (f < NFRAME) ? score2[b * NFRAME + f] : -1e30f;
    float m = v;
    #pragma unroll
    for (int off = 32; off; off >>= 1) m = fmaxf(m, __shfl_xor(m, off));
    float e = (f < NFRAME) ? __expf(v - m) : 0.f;
    float ssum = e;
    #pragma unroll
    for (int off = 32; off; off >>= 1) ssum += __shfl_xor(ssum, off);
    if (f < NFRAME) beta[f] = e / ssum;
  }
  __syncthreads();
  int col = blockIdx.y * 1024 + threadIdx.x * 4;
  float4 av = {0.f, 0.f, 0.f, 0.f};
  #pragma unroll 4
  for (int f = 0; f < NFRAME; ++f) {
    float bw = beta[f];
    float4 v = *(const float4*)(feat + (long)(b * NFRAME + f) * FEAT2 + col);
    av.x += bw * v.x; av.y += bw * v.y; av.z += bw * v.z; av.w += bw * v.w;
  }
  *(float4*)(out + (long)b * FEAT2 + col) = av;
}

// ===========================================================================
// Fallback path (fp32 inputs, inline conversion) — only if ws too small.
// ===========================================================================
#define FBM 128
#define FBN 128
#define FBK 64
#define LDKP 72
__global__ __launch_bounds__(256) void fused_gemm_tanh_score_f32(
    const float* __restrict__ A, const float* __restrict__ W,
    const float* __restrict__ hvec, const float* __restrict__ wa,
    float* __restrict__ score, int M, int K, int rows_per_b)
{
  __shared__ unsigned short ldsA[FBM * LDKP];
  __shared__ unsigned short ldsW[FBN * LDKP];
  const int tid  = threadIdx.x;
  const int lane = tid & 63;
  const int wid  = tid >> 6;
  const int wr   = (wid >> 1) * 64;
  const int wc   = (wid & 1) * 64;
  const int l15  = lane & 15;
  const int q    = lane >> 4;
  const long r0  = (long)blockIdx.y * FBM;
  const int  c0  = blockIdx.x * FBN;

  f32x4 acc[4][4] = {};
  for (int k0 = 0; k0 < K; k0 += FBK) {
    __syncthreads();
    #pragma unroll
    for (int it = 0; it < 8; ++it) {
      int c = tid + it * 256;
      int row = c >> 4, qb = c & 15;
      float4 s = *(const float4*)(A + (r0 + row) * (long)K + k0 + qb * 4);
      ushort4 d; d.x = f2bf(s.x); d.y = f2bf(s.y); d.z = f2bf(s.z); d.w = f2bf(s.w);
      *(ushort4*)(ldsA + row * LDKP + qb * 4) = d;
    }
    #pragma unroll
    for (int it = 0; it < 8; ++it) {
      int c = tid + it * 256;
      int row = c >> 4, qb = c & 15;
      float4 s = *(const float4*)(W + (c0 + row) * (long)K + k0 + qb * 4);
      ushort4 d; d.x = f2bf(s.x); d.y = f2bf(s.y); d.z = f2bf(s.z); d.w = f2bf(s.w);
      *(ushort4*)(ldsW + row * LDKP + qb * 4) = d;
    }
    __syncthreads();
    #pragma unroll
    for (int s = 0; s < 2; ++s) {
      bf16x8 af[4], bfr[4];
      #pragma unroll
      for (int i = 0; i < 4; ++i)
        af[i] = *(const bf16x8*)(ldsA + (wr + i * 16 + l15) * LDKP + s * 32 + q * 8);
      #pragma unroll
      for (int j = 0; j < 4; ++j)
        bfr[j] = *(const bf16x8*)(ldsW + (wc + j * 16 + l15) * LDKP + s * 32 + q * 8);
      #pragma unroll
      for (int i = 0; i < 4; ++i)
        #pragma unroll
        for (int j = 0; j < 4; ++j)
          acc[i][j] = __builtin_amdgcn_mfma_f32_16x16x32_bf16(af[i], bfr[j], acc[i][j], 0, 0, 0);
    }
  }
  float wac[4];
  #pragma unroll
  for (int j = 0; j < 4; ++j) wac[j] = wa[c0 + wc + j * 16 + l15];
  #pragma unroll
  for (int i = 0; i < 4; ++i) {
    #pragma unroll
    for (int r = 0; r < 4; ++r) {
      int row = (int)r0 + wr + i * 16 + q * 4 + r;
      const float* hrow = hvec + (long)(row / rows_per_b) * ATTSZ;
      float part = 0.f;
      #pragma unroll
      for (int j = 0; j < 4; ++j) {
        float x = acc[i][j][r] + hrow[c0 + wc + j * 16 + l15];
        part += fast_tanh(x) * wac[j];
      }
      part += __shfl_xor(part, 1); part += __shfl_xor(part, 2);
      part += __shfl_xor(part, 4); part += __shfl_xor(part, 8);
      if (l15 == 0) atomicAdd(score + row, part);
    }
  }
}

__global__ __launch_bounds__(256) void spatial_softmax_obj_f32(
    const float* __restrict__ obj, const float* __restrict__ score,
    const float* __restrict__ frame, float* __restrict__ feat)
{
  const int bf = blockIdx.x;
  __shared__ float alpha[NBOX];
  if (threadIdx.x < 64) {
    int n = threadIdx.x;
    float v = (n < NBOX) ? score[bf * NBOX + n] : -1e30f;
    float m = v;
    #pragma unroll
    for (int off = 32; off; off >>= 1) m = fmaxf(m, __shfl_xor(m, off));
    float e = (n < NBOX) ? __expf(v - m) : 0.f;
    float ssum = e;
    #pragma unroll
    for (int off = 32; off; off >>= 1) ssum += __shfl_xor(ssum, off);
    if (n < NBOX) alpha[n] = e / ssum;
  }
  __syncthreads();
  const float* base = obj + (long)bf * NBOX * REGION;
  float4 av = {0.f, 0.f, 0.f, 0.f};
  for (int n = 0; n < NBOX; ++n) {
    float al = alpha[n];
    float4 o = *(const float4*)(base + n * REGION + threadIdx.x * 4);
    av.x += al * o.x; av.y += al * o.y; av.z += al * o.z; av.w += al * o.w;
  }
  float* frow = feat + (long)bf * FEAT2;
  *(float4*)(frow + threadIdx.x * 4) = av;
  const float4* fsrc = (const float4*)(frame + (long)bf * 2 * HIDDEN);
  float4* fdst = (float4*)(frow + REGION);
  fdst[threadIdx.x]       = fsrc[threadIdx.x];
  fdst[threadIdx.x + 256] = fsrc[threadIdx.x + 256];
}

__global__ __launch_bounds__(256) void temporal_out_f32(
    const float* __restrict__ score2, const float* __restrict__ feat,
    float* __restrict__ out)
{
  const int b = blockIdx.x;
  __shared__ float beta[NFRAME];
  if (threadIdx.x < 64) {
    int f = threadIdx.x;
    float v = (f < NFRAME) ? score2[b * NFRAME + f] : -1e30f;
    float m = v;
    #pragma unroll
    for (int off = 32; off; off >>= 1) m = fmaxf(m, __shfl_xor(m, off));
    float e = (f < NFRAME) ? __expf(v - m) : 0.f;
    float ssum = e;
    #pragma unroll
    for (int off = 32; off; off >>= 1) ssum += __shfl_xor(ssum, off);
    if (f < NFRAME) beta[f] = e / ssum;
  }
  __syncthreads();
  #pragma unroll
  for (int c = 0; c < 3; ++c) {
    int col = (threadIdx.x + c * 256) * 4;
    float4 av = {0.f, 0.f, 0.f, 0.f};
    for (int f = 0; f < NFRAME; ++f) {
      float bw = beta[f];
      float4 v = *(const float4*)(feat + (long)(b * NFRAME + f) * FEAT2 + col);
      av.x += bw * v.x; av.y += bw * v.y; av.z += bw * v.z; av.w += bw * v.w;
    }
    *(float4*)(out + (long)b * FEAT2 + col) = av;
  }
}

// ---------------------------------------------------------------------------
extern "C" void kernel_launch(void* const* d_in, const int* in_sizes, int n_in,
                              void* d_out, int out_size, void* d_ws, size_t ws_size,
                              hipStream_t stream) {
  const float* frame  = (const float*)d_in[0];
  const float* obj    = (const float*)d_in[1];
  const float* hidden = (const float*)d_in[2];
  const float* s_wh_w = (const float*)d_in[3];
  const float* s_wh_b = (const float*)d_in[4];
  const float* s_wv_w = (const float*)d_in[5];
  const float* s_wv_b = (const float*)d_in[6];
  const float* s_wa_w = (const float*)d_in[7];
  const float* t_wh_w = (const float*)d_in[8];
  const float* t_wh_b = (const float*)d_in[9];
  const float* t_wv_w = (const float*)d_in[10];
  const float* t_wv_b = (const float*)d_in[11];
  const float* t_wa_w = (const float*)d_in[12];
  float* out = (float*)d_out;

  char* p = (char*)d_ws;
  auto alloc = [&](size_t bytes) { char* r = p; p += (bytes + 255) & ~255ull; return r; };
  float* h_s     = (float*)alloc(65536 * 4);
  float* h_t     = (float*)alloc(65536 * 4);
  float* score_s = (float*)alloc((size_t)M_S * 4);   // contiguous with score2
  float* score2  = (float*)alloc((size_t)M_T * 4);
  float* feat    = (float*)alloc((size_t)M_T * FEAT2 * 4);
  unsigned short* objb  = (unsigned short*)alloc((size_t)M_S * REGION * 2);
  unsigned short* featb = (unsigned short*)alloc((size_t)M_T * FEAT2 * 2);
  unsigned short* wvsb  = (unsigned short*)alloc((size_t)ATTSZ * REGION * 2);
  unsigned short* wvtb  = (unsigned short*)alloc((size_t)HIDDEN * FEAT2 * 2);
  size_t needed = (size_t)(p - (char*)d_ws);
  bool fast = needed <= ws_size;

  if (fast) {
    // 6-node chain: prep -> hidden_proj -> gemm_s -> softmax -> gemm_t -> out
    prep<<<PREP_BLKS, 256, 0, stream>>>(obj, objb, s_wv_w, wvsb, t_wv_w, wvtb, score_s);

    hidden_proj<<<dim3(256, 2), 256, 0, stream>>>(
        hidden, s_wh_w, s_wh_b, s_wv_b, t_wh_w, t_wh_b, t_wv_b, h_s, h_t);

    // Spatial: 128x128 tiles, 1-D grid, 8 col-siblings co-located per XCD,
    // 3 blocks/CU via __launch_bounds__(256,3).
    gemm_tanh_score<4, 4, true, 8><<<dim3(8 * (M_S / 128)), 256, 0, stream>>>(
        objb, wvsb, h_s, s_wa_w, score_s, REGION, NFRAME * NBOX);

    spatial_softmax_obj_bf16<<<M_T, 256, 0, stream>>>(objb, score_s, frame, feat, featb);

    // Temporal: 32x128 tiles, grid (8, 64) = 512 blocks.
    gemm_tanh_score<1, 4, false, 8><<<dim3(8, M_T / 32), 256, 0, stream>>>(
        featb, wvtb, h_t, t_wa_w, score2, FEAT2, NFRAME);

    temporal_out<<<dim3(BATCH, 3), 256, 0, stream>>>(score2, feat, out);
  } else {
    hipMemsetAsync(score_s, 0, (size_t)(M_S + M_T) * sizeof(float), stream);
    hidden_proj<<<dim3(256, 2), 256, 0, stream>>>(
        hidden, s_wh_w, s_wh_b, s_wv_b, t_wh_w, t_wh_b, t_wv_b, h_s, h_t);
    fused_gemm_tanh_score_f32<<<dim3(8, M_S / FBM), 256, 0, stream>>>(
        obj, s_wv_w, h_s, s_wa_w, score_s, M_S, REGION, NFRAME * NBOX);
    spatial_softmax_obj_f32<<<M_T, 256, 0, stream>>>(obj, score_s, frame, feat);
    fused_gemm_tanh_score_f32<<<dim3(8, M_T / FBM), 256, 0, stream>>>(
        feat, t_wv_w, h_t, t_wa_w, score2, M_T, FEAT2, NFRAME);
    temporal_out_f32<<<BATCH, 256, 0, stream>>>(score2, feat, out);
  }
}